// Round 6
// baseline (144.819 us; speedup 1.0000x reference)
//
#include <hip/hip_runtime.h>
#include <hip/hip_fp16.h>

#define DIM 64
#define RPB 128          // rows per bucket
#define NCHUNK 256       // edge chunks (and blocks) for count/scatter passes
#define MAXBUK 1024      // max buckets supported by LDS counters

__device__ __forceinline__ float readlane_f(float v, int l) {
  return __uint_as_float(__builtin_amdgcn_readlane(__float_as_uint(v), l));
}

// XCD-contiguous chunk mapping: XCD k (blockIdx%8) handles contiguous chunks.
__device__ __forceinline__ int chunk_id(int blk) {
  return (blk & 7) * (NCHUNK / 8) + (blk >> 3);
}

// ===========================================================================
// Fallback path (tiny workspace): atomic scatter + fused linear/LN/ReLU
// ===========================================================================
__global__ __launch_bounds__(256) void scatter_kernel(
    const float* __restrict__ x, const int* __restrict__ erow,
    const int* __restrict__ ecol, const float* __restrict__ eval,
    float* __restrict__ agg, int E) {
  int t = blockIdx.x * 256 + threadIdx.x;
  int e = t >> 4;
  if (e >= E) return;
  int lid = t & 15;
  int r = erow[e];
  int c = ecol[e];
  float v = eval[e];
  const float4 xv =
      *reinterpret_cast<const float4*>(x + (size_t)c * DIM + lid * 4);
  float* dst = agg + (size_t)r * DIM + lid * 4;
  atomicAdd(dst + 0, v * xv.x);
  atomicAdd(dst + 1, v * xv.y);
  atomicAdd(dst + 2, v * xv.z);
  atomicAdd(dst + 3, v * xv.w);
}

__global__ __launch_bounds__(256) void fused_linear_ln_relu(
    const float* __restrict__ agg, const float* __restrict__ W,
    const float* __restrict__ bias, const float* __restrict__ gamma,
    const float* __restrict__ beta, float* __restrict__ out, int N) {
  __shared__ float Wt[64 * 65];
  for (int i = threadIdx.x; i < 64 * 64; i += 256) {
    int d = i >> 6, k = i & 63;
    Wt[k * 65 + d] = W[i];
  }
  __syncthreads();

  const int wave = threadIdx.x >> 6;
  const int lane = threadIdx.x & 63;
  const int node0 = blockIdx.x * 16 + wave * 4;

  float a0 = 0.f, a1 = 0.f, a2 = 0.f, a3 = 0.f;
  if (node0 + 0 < N) a0 = agg[(size_t)(node0 + 0) * DIM + lane];
  if (node0 + 1 < N) a1 = agg[(size_t)(node0 + 1) * DIM + lane];
  if (node0 + 2 < N) a2 = agg[(size_t)(node0 + 2) * DIM + lane];
  if (node0 + 3 < N) a3 = agg[(size_t)(node0 + 3) * DIM + lane];

  float acc0 = 0.f, acc1 = 0.f, acc2 = 0.f, acc3 = 0.f;
#pragma unroll
  for (int k = 0; k < 64; ++k) {
    float w = Wt[k * 65 + lane];
    acc0 = fmaf(readlane_f(a0, k), w, acc0);
    acc1 = fmaf(readlane_f(a1, k), w, acc1);
    acc2 = fmaf(readlane_f(a2, k), w, acc2);
    acc3 = fmaf(readlane_f(a3, k), w, acc3);
  }

  const float bv = bias[lane];
  const float gv = gamma[lane];
  const float btv = beta[lane];
  float accs[4] = {acc0, acc1, acc2, acc3};
#pragma unroll
  for (int j = 0; j < 4; ++j) {
    int node = node0 + j;
    if (node >= N) continue;
    float h = accs[j] + bv;
    float s1 = h, s2 = h * h;
#pragma unroll
    for (int off = 32; off; off >>= 1) {
      s1 += __shfl_xor(s1, off, 64);
      s2 += __shfl_xor(s2, off, 64);
    }
    float mu = s1 * (1.0f / 64.0f);
    float var = s2 * (1.0f / 64.0f) - mu * mu;
    float inv = rsqrtf(var + 1e-5f);
    float y = (h - mu) * inv * gv + btv;
    out[(size_t)node * DIM + lane] = fmaxf(y, 0.0f);
  }
}

// ===========================================================================
// x -> fp16 mirror (halves the random-gather footprint: 256B/row -> 128B/row)
// ===========================================================================
__global__ __launch_bounds__(256) void cvt_x_kernel(const float* __restrict__ x,
                                                    __half* __restrict__ xh,
                                                    int n4) {
  int i = blockIdx.x * 256 + threadIdx.x;
  if (i >= n4) return;
  float4 f = reinterpret_cast<const float4*>(x)[i];
  __half2 a = __floats2half2_rn(f.x, f.y);
  __half2 b = __floats2half2_rn(f.z, f.w);
  uint2 o;
  o.x = *reinterpret_cast<unsigned*>(&a);
  o.y = *reinterpret_cast<unsigned*>(&b);
  reinterpret_cast<uint2*>(xh)[i] = o;
}

// ===========================================================================
// Two-level deterministic-position sort
// ===========================================================================

// 1) per-chunk bucket histogram via LDS counters -> counts[bucket*NCHUNK+cid]
//    (writes EVERY entry -> no memset needed)
__global__ __launch_bounds__(256) void count_coarse(
    const int* __restrict__ erow, int* __restrict__ counts, int E, int cpb,
    int NB) {
  __shared__ int cnt[MAXBUK];
  for (int i = threadIdx.x; i < NB; i += 256) cnt[i] = 0;
  __syncthreads();
  const int cid = chunk_id(blockIdx.x);
  const int base = cid * cpb;
  const int end = min(E, base + cpb);
  for (int e = base + threadIdx.x; e < end; e += 256)
    atomicAdd(&cnt[erow[e] >> 7], 1);
  __syncthreads();
  for (int i = threadIdx.x; i < NB; i += 256)
    counts[i * NCHUNK + cid] = cnt[i];
}

// 2a) per-block exclusive scan, 2048 elems/block (8 per thread)
__global__ __launch_bounds__(256) void scan1b_kernel(int* __restrict__ data,
                                                     int* __restrict__ partials,
                                                     int n) {
  __shared__ int wsum[4];
  const int t = threadIdx.x;
  const int base = blockIdx.x * 2048 + t * 8;
  int v[8];
  int s = 0;
#pragma unroll
  for (int j = 0; j < 8; ++j) {
    v[j] = (base + j < n) ? data[base + j] : 0;
    s += v[j];
  }
  int ps = s;
  const int lane = t & 63;
#pragma unroll
  for (int off = 1; off < 64; off <<= 1) {
    int nn = __shfl_up(ps, off, 64);
    if (lane >= off) ps += nn;
  }
  if (lane == 63) wsum[t >> 6] = ps;
  __syncthreads();
  int woff = 0;
  for (int w = 0; w < (t >> 6); ++w) woff += wsum[w];
  int ex = woff + ps - s;
#pragma unroll
  for (int j = 0; j < 8; ++j) {
    if (base + j < n) data[base + j] = ex;
    ex += v[j];
  }
  if (t == 255) partials[blockIdx.x] = woff + ps;
}

// 2b) exclusive scan of block totals (single block; nb <= 256)
__global__ __launch_bounds__(256) void scan2_kernel(int* __restrict__ partials,
                                                    int nb) {
  __shared__ int wsum[4];
  int t = threadIdx.x;
  int v = (t < nb) ? partials[t] : 0;
  int ps = v;
  int lane = t & 63;
#pragma unroll
  for (int off = 1; off < 64; off <<= 1) {
    int n = __shfl_up(ps, off, 64);
    if (lane >= off) ps += n;
  }
  if (lane == 63) wsum[t >> 6] = ps;
  __syncthreads();
  int woff = 0;
  for (int w = 0; w < (t >> 6); ++w) woff += wsum[w];
  if (t < nb) partials[t] = woff + ps - v;
}

// 2c) finalize scanned counts; extract bucket bases
__global__ __launch_bounds__(256) void scan3b_kernel(
    int* __restrict__ data, const int* __restrict__ partials,
    int* __restrict__ bucket_base, int NC, int NB, int E) {
  int i = blockIdx.x * 256 + threadIdx.x;
  if (i < NC) {
    int v = data[i] + partials[i >> 11];
    data[i] = v;
    if ((i & (NCHUNK - 1)) == 0) bucket_base[i / NCHUNK] = v;
  }
  if (i == 0) bucket_base[NB] = E;
}

// 3) coarse scatter: deterministic per-(bucket,chunk) contiguous ranges.
__global__ __launch_bounds__(256) void scatter_coarse(
    const int* __restrict__ erow, const int* __restrict__ ecol,
    const float* __restrict__ eval, const int* __restrict__ scanned,
    uint2* __restrict__ binned, int E, int cpb, int NB) {
  __shared__ int cur[MAXBUK];
  const int cid = chunk_id(blockIdx.x);
  for (int i = threadIdx.x; i < NB; i += 256)
    cur[i] = scanned[i * NCHUNK + cid];
  __syncthreads();
  const int base = cid * cpb;
  const int end = min(E, base + cpb);
  for (int e = base + threadIdx.x; e < end; e += 256) {
    int r = erow[e];
    uint2 p;
    p.x = ((unsigned)ecol[e] << 7) | (unsigned)(r & 127);
    p.y = __float_as_uint(eval[e]);
    int pos = atomicAdd(&cur[r >> 7], 1);
    binned[pos] = p;
  }
}

// 4) within-bucket exact CSR sort + row_start emission.
__global__ __launch_bounds__(256) void sort_fine(
    const uint2* __restrict__ binned, const int* __restrict__ bucket_base,
    uint2* __restrict__ csr, int* __restrict__ row_start, int N, int E) {
  __shared__ int hist[RPB];
  __shared__ int cursor[RPB];
  const int b = blockIdx.x;
  const int s = bucket_base[b];
  const int en = bucket_base[b + 1];
  const int t = threadIdx.x;
  if (t < RPB) hist[t] = 0;
  __syncthreads();
  for (int e = s + t; e < en; e += 256)
    atomicAdd(&hist[binned[e].x & 127], 1);
  __syncthreads();
  if (t == 0) {
    int run = 0;
    for (int i = 0; i < RPB; ++i) {
      int c = hist[i];
      cursor[i] = run;
      run += c;
    }
  }
  __syncthreads();
  if (t < RPB) {
    int node = b * RPB + t;
    if (node < N) row_start[node] = s + cursor[t];
  }
  if (b == 0 && t == 0) row_start[N] = E;
  __syncthreads();
  for (int e = s + t; e < en; e += 256) {
    uint2 p = binned[e];
    int rl = (int)(p.x & 127);
    int pos = s + atomicAdd(&cursor[rl], 1);
    uint2 q;
    q.x = p.x >> 7;  // col
    q.y = p.y;       // val bits
    csr[pos] = q;
  }
}

// 5) fused gather (SpMM, ILP-8) + Linear + LayerNorm + ReLU.
//    Templated on gather dtype: fp16 mirror (preferred) or fp32 x.
template <typename XT>
__global__ __launch_bounds__(256) void fused_gather_linear_ln(
    const XT* __restrict__ xg, const uint2* __restrict__ csr,
    const int* __restrict__ row_start, const float* __restrict__ W,
    const float* __restrict__ bias, const float* __restrict__ gamma,
    const float* __restrict__ beta, float* __restrict__ out, int N) {
  __shared__ float Wt[64 * 65];
  __shared__ float xch[4][256];
  for (int i = threadIdx.x; i < 64 * 64; i += 256) {
    int d = i >> 6, k = i & 63;
    Wt[k * 65 + d] = W[i];
  }

  const int wave = threadIdx.x >> 6;
  const int lane = threadIdx.x & 63;
  const int grp = lane >> 4;
  const int lid = lane & 15;
  const int node0 = blockIdx.x * 16 + wave * 4;
  const int node = node0 + grp;

  float4 acc = make_float4(0.f, 0.f, 0.f, 0.f);
  if (node < N) {
    int s = row_start[node];
    int en = row_start[node + 1];
    int j = s;
    for (; j + 8 <= en; j += 8) {
      uint2 p[8];
#pragma unroll
      for (int i = 0; i < 8; ++i) p[i] = csr[j + i];
      if constexpr (sizeof(XT) == 2) {
        uint2 xv[8];
#pragma unroll
        for (int i = 0; i < 8; ++i)
          xv[i] = *reinterpret_cast<const uint2*>(xg + (size_t)p[i].x * DIM +
                                                  lid * 4);
#pragma unroll
        for (int i = 0; i < 8; ++i) {
          float v = __uint_as_float(p[i].y);
          float2 f01 = __half22float2(*reinterpret_cast<__half2*>(&xv[i].x));
          float2 f23 = __half22float2(*reinterpret_cast<__half2*>(&xv[i].y));
          acc.x = fmaf(v, f01.x, acc.x);
          acc.y = fmaf(v, f01.y, acc.y);
          acc.z = fmaf(v, f23.x, acc.z);
          acc.w = fmaf(v, f23.y, acc.w);
        }
      } else {
        float4 xv[8];
#pragma unroll
        for (int i = 0; i < 8; ++i)
          xv[i] = *reinterpret_cast<const float4*>(
              (const float*)xg + (size_t)p[i].x * DIM + lid * 4);
#pragma unroll
        for (int i = 0; i < 8; ++i) {
          float v = __uint_as_float(p[i].y);
          acc.x = fmaf(v, xv[i].x, acc.x);
          acc.y = fmaf(v, xv[i].y, acc.y);
          acc.z = fmaf(v, xv[i].z, acc.z);
          acc.w = fmaf(v, xv[i].w, acc.w);
        }
      }
    }
    for (; j < en; ++j) {
      uint2 p0 = csr[j];
      float v0 = __uint_as_float(p0.y);
      if constexpr (sizeof(XT) == 2) {
        uint2 h =
            *reinterpret_cast<const uint2*>(xg + (size_t)p0.x * DIM + lid * 4);
        float2 f01 = __half22float2(*reinterpret_cast<__half2*>(&h.x));
        float2 f23 = __half22float2(*reinterpret_cast<__half2*>(&h.y));
        acc.x = fmaf(v0, f01.x, acc.x);
        acc.y = fmaf(v0, f01.y, acc.y);
        acc.z = fmaf(v0, f23.x, acc.z);
        acc.w = fmaf(v0, f23.y, acc.w);
      } else {
        const float4 x0 = *reinterpret_cast<const float4*>(
            (const float*)xg + (size_t)p0.x * DIM + lid * 4);
        acc.x = fmaf(v0, x0.x, acc.x);
        acc.y = fmaf(v0, x0.y, acc.y);
        acc.z = fmaf(v0, x0.z, acc.z);
        acc.w = fmaf(v0, x0.w, acc.w);
      }
    }
  }
  __syncthreads();  // covers Wt staging too
  *reinterpret_cast<float4*>(&xch[wave][grp * 64 + lid * 4]) = acc;
  __syncthreads();

  float a0 = xch[wave][0 * 64 + lane];
  float a1 = xch[wave][1 * 64 + lane];
  float a2 = xch[wave][2 * 64 + lane];
  float a3 = xch[wave][3 * 64 + lane];

  float acc0 = 0.f, acc1 = 0.f, acc2 = 0.f, acc3 = 0.f;
#pragma unroll
  for (int k = 0; k < 64; ++k) {
    float w = Wt[k * 65 + lane];
    acc0 = fmaf(readlane_f(a0, k), w, acc0);
    acc1 = fmaf(readlane_f(a1, k), w, acc1);
    acc2 = fmaf(readlane_f(a2, k), w, acc2);
    acc3 = fmaf(readlane_f(a3, k), w, acc3);
  }

  const float bv = bias[lane];
  const float gv = gamma[lane];
  const float btv = beta[lane];
  float accs[4] = {acc0, acc1, acc2, acc3};
#pragma unroll
  for (int jj = 0; jj < 4; ++jj) {
    int nd = node0 + jj;
    if (nd >= N) continue;
    float h = accs[jj] + bv;
    float s1 = h, s2 = h * h;
#pragma unroll
    for (int off = 32; off; off >>= 1) {
      s1 += __shfl_xor(s1, off, 64);
      s2 += __shfl_xor(s2, off, 64);
    }
    float mu = s1 * (1.0f / 64.0f);
    float var = s2 * (1.0f / 64.0f) - mu * mu;
    float inv = rsqrtf(var + 1e-5f);
    float y = (h - mu) * inv * gv + btv;
    out[(size_t)nd * DIM + lane] = fmaxf(y, 0.0f);
  }
}

// ===========================================================================
extern "C" void kernel_launch(void* const* d_in, const int* in_sizes, int n_in,
                              void* d_out, int out_size, void* d_ws,
                              size_t ws_size, hipStream_t stream) {
  const float* x = (const float*)d_in[0];
  const int* erow = (const int*)d_in[1];
  const int* ecol = (const int*)d_in[2];
  const float* eval = (const float*)d_in[3];
  const float* W = (const float*)d_in[4];
  const float* bias = (const float*)d_in[5];
  const float* gamma = (const float*)d_in[6];
  const float* beta = (const float*)d_in[7];
  float* out = (float*)d_out;

  const int N = in_sizes[0] / DIM;
  const int E = in_sizes[1];

  const int NB = (N + RPB - 1) / RPB;   // row buckets
  const int NC = NB * NCHUNK;           // (bucket, chunk) counters
  const int nblk_scan = (NC + 2047) / 2048;
  const int cpb = (E + NCHUNK - 1) / NCHUNK;

  // ws layout: counts[NC] | partials[256] | bucket_base[NB+1] |
  //            row_start[N+1] | pad16 | binned[E] u2 | csr[E] u2 | xh[N*DIM] h
  size_t int_words = (size_t)NC + 256 + (NB + 1) + (N + 1);
  size_t u2_off = ((int_words * sizeof(int)) + 15) & ~(size_t)15;
  size_t need_base = u2_off + 2 * (size_t)E * sizeof(uint2);
  size_t xh_off = (need_base + 15) & ~(size_t)15;
  size_t need_fp16 = xh_off + (size_t)N * DIM * sizeof(__half);

  if (ws_size >= need_base && NB <= MAXBUK && nblk_scan <= 256) {
    int* counts = (int*)d_ws;                       // NC
    int* partials = counts + NC;                    // 256
    int* bucket_base = partials + 256;              // NB+1
    int* row_start = bucket_base + (NB + 1);        // N+1
    uint2* binned = (uint2*)((char*)d_ws + u2_off); // E
    uint2* csr = binned + E;                        // E
    const bool use_fp16 = (ws_size >= need_fp16);
    __half* xh = (__half*)((char*)d_ws + xh_off);

    if (use_fp16) {
      int n4 = N * DIM / 4;
      cvt_x_kernel<<<(n4 + 255) / 256, 256, 0, stream>>>(x, xh, n4);
    }
    count_coarse<<<NCHUNK, 256, 0, stream>>>(erow, counts, E, cpb, NB);
    scan1b_kernel<<<nblk_scan, 256, 0, stream>>>(counts, partials, NC);
    scan2_kernel<<<1, 256, 0, stream>>>(partials, nblk_scan);
    scan3b_kernel<<<(NC + 255) / 256, 256, 0, stream>>>(counts, partials,
                                                        bucket_base, NC, NB, E);
    scatter_coarse<<<NCHUNK, 256, 0, stream>>>(erow, ecol, eval, counts,
                                               binned, E, cpb, NB);
    sort_fine<<<NB, 256, 0, stream>>>(binned, bucket_base, csr, row_start, N,
                                      E);
    if (use_fp16) {
      fused_gather_linear_ln<__half><<<(N + 15) / 16, 256, 0, stream>>>(
          xh, csr, row_start, W, bias, gamma, beta, out, N);
    } else {
      fused_gather_linear_ln<float><<<(N + 15) / 16, 256, 0, stream>>>(
          x, csr, row_start, W, bias, gamma, beta, out, N);
    }
  } else {
    const size_t agg_bytes = (size_t)N * DIM * sizeof(float);
    float* agg = (ws_size >= agg_bytes) ? (float*)d_ws : out;
    hipMemsetAsync(agg, 0, agg_bytes, stream);
    long long total = (long long)E * 16;
    int blocks = (int)((total + 255) / 256);
    scatter_kernel<<<blocks, 256, 0, stream>>>(x, erow, ecol, eval, agg, E);
    fused_linear_ln_relu<<<(N + 15) / 16, 256, 0, stream>>>(agg, W, bias,
                                                            gamma, beta, out, N);
  }
}

// Round 7
// 129.722 us; speedup vs baseline: 1.1164x; 1.1164x over previous
//
#include <hip/hip_runtime.h>
#include <hip/hip_fp16.h>

#define DIM 64
#define RPB 128          // rows per bucket
#define NCHUNK 256       // edge chunks (and blocks) for count/scatter passes
#define MAXBUK 1024      // max buckets supported by LDS counters

typedef _Float16 half8_t __attribute__((ext_vector_type(8)));
typedef float f32x4_t __attribute__((ext_vector_type(4)));

__device__ __forceinline__ float readlane_f(float v, int l) {
  return __uint_as_float(__builtin_amdgcn_readlane(__float_as_uint(v), l));
}

// XCD-contiguous chunk mapping: XCD k (blockIdx%8) handles contiguous chunks.
__device__ __forceinline__ int chunk_id(int blk) {
  return (blk & 7) * (NCHUNK / 8) + (blk >> 3);
}

// ===========================================================================
// Fallback path (tiny workspace): atomic scatter + fused linear/LN/ReLU
// ===========================================================================
__global__ __launch_bounds__(256) void scatter_kernel(
    const float* __restrict__ x, const int* __restrict__ erow,
    const int* __restrict__ ecol, const float* __restrict__ eval,
    float* __restrict__ agg, int E) {
  int t = blockIdx.x * 256 + threadIdx.x;
  int e = t >> 4;
  if (e >= E) return;
  int lid = t & 15;
  int r = erow[e];
  int c = ecol[e];
  float v = eval[e];
  const float4 xv =
      *reinterpret_cast<const float4*>(x + (size_t)c * DIM + lid * 4);
  float* dst = agg + (size_t)r * DIM + lid * 4;
  atomicAdd(dst + 0, v * xv.x);
  atomicAdd(dst + 1, v * xv.y);
  atomicAdd(dst + 2, v * xv.z);
  atomicAdd(dst + 3, v * xv.w);
}

__global__ __launch_bounds__(256) void fused_linear_ln_relu(
    const float* __restrict__ agg, const float* __restrict__ W,
    const float* __restrict__ bias, const float* __restrict__ gamma,
    const float* __restrict__ beta, float* __restrict__ out, int N) {
  __shared__ float Wt[64 * 65];
  for (int i = threadIdx.x; i < 64 * 64; i += 256) {
    int d = i >> 6, k = i & 63;
    Wt[k * 65 + d] = W[i];
  }
  __syncthreads();

  const int wave = threadIdx.x >> 6;
  const int lane = threadIdx.x & 63;
  const int node0 = blockIdx.x * 16 + wave * 4;

  float a0 = 0.f, a1 = 0.f, a2 = 0.f, a3 = 0.f;
  if (node0 + 0 < N) a0 = agg[(size_t)(node0 + 0) * DIM + lane];
  if (node0 + 1 < N) a1 = agg[(size_t)(node0 + 1) * DIM + lane];
  if (node0 + 2 < N) a2 = agg[(size_t)(node0 + 2) * DIM + lane];
  if (node0 + 3 < N) a3 = agg[(size_t)(node0 + 3) * DIM + lane];

  float acc0 = 0.f, acc1 = 0.f, acc2 = 0.f, acc3 = 0.f;
#pragma unroll
  for (int k = 0; k < 64; ++k) {
    float w = Wt[k * 65 + lane];
    acc0 = fmaf(readlane_f(a0, k), w, acc0);
    acc1 = fmaf(readlane_f(a1, k), w, acc1);
    acc2 = fmaf(readlane_f(a2, k), w, acc2);
    acc3 = fmaf(readlane_f(a3, k), w, acc3);
  }

  const float bv = bias[lane];
  const float gv = gamma[lane];
  const float btv = beta[lane];
  float accs[4] = {acc0, acc1, acc2, acc3};
#pragma unroll
  for (int j = 0; j < 4; ++j) {
    int node = node0 + j;
    if (node >= N) continue;
    float h = accs[j] + bv;
    float s1 = h, s2 = h * h;
#pragma unroll
    for (int off = 32; off; off >>= 1) {
      s1 += __shfl_xor(s1, off, 64);
      s2 += __shfl_xor(s2, off, 64);
    }
    float mu = s1 * (1.0f / 64.0f);
    float var = s2 * (1.0f / 64.0f) - mu * mu;
    float inv = rsqrtf(var + 1e-5f);
    float y = (h - mu) * inv * gv + btv;
    out[(size_t)node * DIM + lane] = fmaxf(y, 0.0f);
  }
}

// ===========================================================================
// x -> fp16 mirror (halves the random-gather footprint)
// ===========================================================================
__global__ __launch_bounds__(256) void cvt_x_kernel(const float* __restrict__ x,
                                                    __half* __restrict__ xh,
                                                    int n4) {
  int i = blockIdx.x * 256 + threadIdx.x;
  if (i >= n4) return;
  float4 f = reinterpret_cast<const float4*>(x)[i];
  __half2 a = __floats2half2_rn(f.x, f.y);
  __half2 b = __floats2half2_rn(f.z, f.w);
  uint2 o;
  o.x = *reinterpret_cast<unsigned*>(&a);
  o.y = *reinterpret_cast<unsigned*>(&b);
  reinterpret_cast<uint2*>(xh)[i] = o;
}

// ===========================================================================
// Two-level deterministic-position sort (unchanged from round 4/5)
// ===========================================================================
__global__ __launch_bounds__(256) void count_coarse(
    const int* __restrict__ erow, int* __restrict__ counts, int E, int cpb,
    int NB) {
  __shared__ int cnt[MAXBUK];
  for (int i = threadIdx.x; i < NB; i += 256) cnt[i] = 0;
  __syncthreads();
  const int cid = chunk_id(blockIdx.x);
  const int base = cid * cpb;
  const int end = min(E, base + cpb);
  for (int e = base + threadIdx.x; e < end; e += 256)
    atomicAdd(&cnt[erow[e] >> 7], 1);
  __syncthreads();
  for (int i = threadIdx.x; i < NB; i += 256)
    counts[i * NCHUNK + cid] = cnt[i];
}

__global__ __launch_bounds__(256) void scan1b_kernel(int* __restrict__ data,
                                                     int* __restrict__ partials,
                                                     int n) {
  __shared__ int wsum[4];
  const int t = threadIdx.x;
  const int base = blockIdx.x * 2048 + t * 8;
  int v[8];
  int s = 0;
#pragma unroll
  for (int j = 0; j < 8; ++j) {
    v[j] = (base + j < n) ? data[base + j] : 0;
    s += v[j];
  }
  int ps = s;
  const int lane = t & 63;
#pragma unroll
  for (int off = 1; off < 64; off <<= 1) {
    int nn = __shfl_up(ps, off, 64);
    if (lane >= off) ps += nn;
  }
  if (lane == 63) wsum[t >> 6] = ps;
  __syncthreads();
  int woff = 0;
  for (int w = 0; w < (t >> 6); ++w) woff += wsum[w];
  int ex = woff + ps - s;
#pragma unroll
  for (int j = 0; j < 8; ++j) {
    if (base + j < n) data[base + j] = ex;
    ex += v[j];
  }
  if (t == 255) partials[blockIdx.x] = woff + ps;
}

__global__ __launch_bounds__(256) void scan2_kernel(int* __restrict__ partials,
                                                    int nb) {
  __shared__ int wsum[4];
  int t = threadIdx.x;
  int v = (t < nb) ? partials[t] : 0;
  int ps = v;
  int lane = t & 63;
#pragma unroll
  for (int off = 1; off < 64; off <<= 1) {
    int n = __shfl_up(ps, off, 64);
    if (lane >= off) ps += n;
  }
  if (lane == 63) wsum[t >> 6] = ps;
  __syncthreads();
  int woff = 0;
  for (int w = 0; w < (t >> 6); ++w) woff += wsum[w];
  if (t < nb) partials[t] = woff + ps - v;
}

__global__ __launch_bounds__(256) void scan3b_kernel(
    int* __restrict__ data, const int* __restrict__ partials,
    int* __restrict__ bucket_base, int NC, int NB, int E) {
  int i = blockIdx.x * 256 + threadIdx.x;
  if (i < NC) {
    int v = data[i] + partials[i >> 11];
    data[i] = v;
    if ((i & (NCHUNK - 1)) == 0) bucket_base[i / NCHUNK] = v;
  }
  if (i == 0) bucket_base[NB] = E;
}

__global__ __launch_bounds__(256) void scatter_coarse(
    const int* __restrict__ erow, const int* __restrict__ ecol,
    const float* __restrict__ eval, const int* __restrict__ scanned,
    uint2* __restrict__ binned, int E, int cpb, int NB) {
  __shared__ int cur[MAXBUK];
  const int cid = chunk_id(blockIdx.x);
  for (int i = threadIdx.x; i < NB; i += 256)
    cur[i] = scanned[i * NCHUNK + cid];
  __syncthreads();
  const int base = cid * cpb;
  const int end = min(E, base + cpb);
  for (int e = base + threadIdx.x; e < end; e += 256) {
    int r = erow[e];
    uint2 p;
    p.x = ((unsigned)ecol[e] << 7) | (unsigned)(r & 127);
    p.y = __float_as_uint(eval[e]);
    int pos = atomicAdd(&cur[r >> 7], 1);
    binned[pos] = p;
  }
}

__global__ __launch_bounds__(256) void sort_fine(
    const uint2* __restrict__ binned, const int* __restrict__ bucket_base,
    uint2* __restrict__ csr, int* __restrict__ row_start, int N, int E) {
  __shared__ int hist[RPB];
  __shared__ int cursor[RPB];
  const int b = blockIdx.x;
  const int s = bucket_base[b];
  const int en = bucket_base[b + 1];
  const int t = threadIdx.x;
  if (t < RPB) hist[t] = 0;
  __syncthreads();
  for (int e = s + t; e < en; e += 256)
    atomicAdd(&hist[binned[e].x & 127], 1);
  __syncthreads();
  if (t == 0) {
    int run = 0;
    for (int i = 0; i < RPB; ++i) {
      int c = hist[i];
      cursor[i] = run;
      run += c;
    }
  }
  __syncthreads();
  if (t < RPB) {
    int node = b * RPB + t;
    if (node < N) row_start[node] = s + cursor[t];
  }
  if (b == 0 && t == 0) row_start[N] = E;
  __syncthreads();
  for (int e = s + t; e < en; e += 256) {
    uint2 p = binned[e];
    int rl = (int)(p.x & 127);
    int pos = s + atomicAdd(&cursor[rl], 1);
    uint2 q;
    q.x = p.x >> 7;  // col
    q.y = p.y;       // val bits
    csr[pos] = q;
  }
}

// ===========================================================================
// Fused gather (SpMM, ILP-8) + MFMA Linear + LayerNorm + ReLU.
// One block = 4 waves; each wave owns 16 nodes.
// Per wave: 16-lane groups gather 4 nodes each -> LDS A-tile [16][72] fp16
// (pad 72: 2-way bank = free). Linear = 8x mfma_f32_16x16x32_f16:
//   A: row=lane&15 (node), k=8*(lane>>4)+j (+32 per K-half)
//   B: col=lane&15 (dim),  k=8*(lane>>4)+j (+32 per K-half)  [pre-packed LDS]
//   D: col=lane&15 (dim),  row=4*(lane>>4)+reg (node)        [m89-verified]
// LN: 16-lane __shfl_xor reductions per node row.
// ===========================================================================
template <typename XT>
__global__ __launch_bounds__(256) void fused_gather_mfma_ln(
    const XT* __restrict__ xg, const uint2* __restrict__ csr,
    const int* __restrict__ row_start, const float* __restrict__ W,
    const float* __restrict__ bias, const float* __restrict__ gamma,
    const float* __restrict__ beta, float* __restrict__ out, int N) {
  __shared__ _Float16 Wp[4 * 2 * 64 * 8];   // B fragments, 8 KB
  __shared__ _Float16 A_lds[4][16 * 72];    // per-wave A tile, 9 KB total

  const int tid = threadIdx.x;

  // Pack W into B-fragment order: Wp[((t*2+h)*64+l)*8 + j] =
  //   W[d][k],  d=(l&15)+16t, k=8*(l>>4)+j+32h   (8 contiguous f32 per triple)
  for (int p = tid; p < 512; p += 256) {
    int t = p >> 7, h = (p >> 6) & 1, l = p & 63;
    int d = (l & 15) + 16 * t;
    int k0 = ((l >> 4) << 3) + 32 * h;
    const float* wr = W + d * 64 + k0;
    _Float16* dst = &Wp[p * 8];
#pragma unroll
    for (int j = 0; j < 8; ++j) dst[j] = (_Float16)wr[j];
  }

  const int wave = tid >> 6;
  const int lane = tid & 63;
  const int g = lane >> 4;   // gather group
  const int lid = lane & 15; // 16 lanes x 4 dims = 64 k's
  const int wbase = blockIdx.x * 64 + wave * 16;

  // ---- gather: each group does 4 nodes sequentially ----
#pragma unroll 1
  for (int m = 0; m < 4; ++m) {
    const int row = g * 4 + m;
    const int node = wbase + row;
    float4 acc = make_float4(0.f, 0.f, 0.f, 0.f);
    if (node < N) {
      int s = row_start[node];
      int en = row_start[node + 1];
      int j = s;
      for (; j + 8 <= en; j += 8) {
        uint2 p[8];
#pragma unroll
        for (int i = 0; i < 8; ++i) p[i] = csr[j + i];
        if constexpr (sizeof(XT) == 2) {
          uint2 xv[8];
#pragma unroll
          for (int i = 0; i < 8; ++i)
            xv[i] = *reinterpret_cast<const uint2*>(xg + (size_t)p[i].x * DIM +
                                                    lid * 4);
#pragma unroll
          for (int i = 0; i < 8; ++i) {
            float v = __uint_as_float(p[i].y);
            float2 f01 = __half22float2(*reinterpret_cast<__half2*>(&xv[i].x));
            float2 f23 = __half22float2(*reinterpret_cast<__half2*>(&xv[i].y));
            acc.x = fmaf(v, f01.x, acc.x);
            acc.y = fmaf(v, f01.y, acc.y);
            acc.z = fmaf(v, f23.x, acc.z);
            acc.w = fmaf(v, f23.y, acc.w);
          }
        } else {
          float4 xv[8];
#pragma unroll
          for (int i = 0; i < 8; ++i)
            xv[i] = *reinterpret_cast<const float4*>(
                (const float*)xg + (size_t)p[i].x * DIM + lid * 4);
#pragma unroll
          for (int i = 0; i < 8; ++i) {
            float v = __uint_as_float(p[i].y);
            acc.x = fmaf(v, xv[i].x, acc.x);
            acc.y = fmaf(v, xv[i].y, acc.y);
            acc.z = fmaf(v, xv[i].z, acc.z);
            acc.w = fmaf(v, xv[i].w, acc.w);
          }
        }
      }
      for (; j < en; ++j) {
        uint2 p0 = csr[j];
        float v0 = __uint_as_float(p0.y);
        if constexpr (sizeof(XT) == 2) {
          uint2 hbits = *reinterpret_cast<const uint2*>(
              xg + (size_t)p0.x * DIM + lid * 4);
          float2 f01 = __half22float2(*reinterpret_cast<__half2*>(&hbits.x));
          float2 f23 = __half22float2(*reinterpret_cast<__half2*>(&hbits.y));
          acc.x = fmaf(v0, f01.x, acc.x);
          acc.y = fmaf(v0, f01.y, acc.y);
          acc.z = fmaf(v0, f23.x, acc.z);
          acc.w = fmaf(v0, f23.y, acc.w);
        } else {
          const float4 x0 = *reinterpret_cast<const float4*>(
              (const float*)xg + (size_t)p0.x * DIM + lid * 4);
          acc.x = fmaf(v0, x0.x, acc.x);
          acc.y = fmaf(v0, x0.y, acc.y);
          acc.z = fmaf(v0, x0.z, acc.z);
          acc.w = fmaf(v0, x0.w, acc.w);
        }
      }
    }
    // store agg row (fp16) into A tile: k = lid*4..+3, 8B aligned
    __half2 lo = __floats2half2_rn(acc.x, acc.y);
    __half2 hi = __floats2half2_rn(acc.z, acc.w);
    uint2 pk;
    pk.x = *reinterpret_cast<unsigned*>(&lo);
    pk.y = *reinterpret_cast<unsigned*>(&hi);
    *reinterpret_cast<uint2*>(&A_lds[wave][row * 72 + lid * 4]) = pk;
  }

  __syncthreads();  // covers Wp packing + A tiles

  // ---- MFMA: 16 nodes x 64 dims = 4 dim-tiles x 2 K-halves ----
  half8_t bf[4][2];
#pragma unroll
  for (int t = 0; t < 4; ++t)
#pragma unroll
    for (int h = 0; h < 2; ++h)
      bf[t][h] =
          *reinterpret_cast<const half8_t*>(&Wp[((t * 2 + h) * 64 + lane) * 8]);

  const int arow = lane & 15;
  const int koff = (lane >> 4) * 8;
  half8_t a0 =
      *reinterpret_cast<const half8_t*>(&A_lds[wave][arow * 72 + koff]);
  half8_t a1 =
      *reinterpret_cast<const half8_t*>(&A_lds[wave][arow * 72 + koff + 32]);

  f32x4_t dacc[4];
#pragma unroll
  for (int t = 0; t < 4; ++t) {
    f32x4_t z = {0.f, 0.f, 0.f, 0.f};
    z = __builtin_amdgcn_mfma_f32_16x16x32_f16(a0, bf[t][0], z, 0, 0, 0);
    z = __builtin_amdgcn_mfma_f32_16x16x32_f16(a1, bf[t][1], z, 0, 0, 0);
    dacc[t] = z;
  }

  // ---- epilogue: bias + LN + ReLU ----
  const int q = lane >> 4;   // node quadrant
  const int c = lane & 15;   // dim low
  float bv[4], gv[4], btv[4];
#pragma unroll
  for (int t = 0; t < 4; ++t) {
    int d = c + 16 * t;
    bv[t] = bias[d];
    gv[t] = gamma[d];
    btv[t] = beta[d];
  }

#pragma unroll
  for (int j = 0; j < 4; ++j) {
    const int node = wbase + q * 4 + j;
    float h0 = dacc[0][j] + bv[0];
    float h1 = dacc[1][j] + bv[1];
    float h2 = dacc[2][j] + bv[2];
    float h3 = dacc[3][j] + bv[3];
    float s1 = h0 + h1 + h2 + h3;
    float s2 = fmaf(h0, h0, fmaf(h1, h1, fmaf(h2, h2, h3 * h3)));
#pragma unroll
    for (int off = 1; off < 16; off <<= 1) {
      s1 += __shfl_xor(s1, off, 16);
      s2 += __shfl_xor(s2, off, 16);
    }
    float mu = s1 * (1.0f / 64.0f);
    float var = s2 * (1.0f / 64.0f) - mu * mu;
    float inv = rsqrtf(var + 1e-5f);
    if (node < N) {
      float* o = out + (size_t)node * DIM + c;
      o[0]  = fmaxf((h0 - mu) * inv * gv[0] + btv[0], 0.f);
      o[16] = fmaxf((h1 - mu) * inv * gv[1] + btv[1], 0.f);
      o[32] = fmaxf((h2 - mu) * inv * gv[2] + btv[2], 0.f);
      o[48] = fmaxf((h3 - mu) * inv * gv[3] + btv[3], 0.f);
    }
  }
}

// ===========================================================================
extern "C" void kernel_launch(void* const* d_in, const int* in_sizes, int n_in,
                              void* d_out, int out_size, void* d_ws,
                              size_t ws_size, hipStream_t stream) {
  const float* x = (const float*)d_in[0];
  const int* erow = (const int*)d_in[1];
  const int* ecol = (const int*)d_in[2];
  const float* eval = (const float*)d_in[3];
  const float* W = (const float*)d_in[4];
  const float* bias = (const float*)d_in[5];
  const float* gamma = (const float*)d_in[6];
  const float* beta = (const float*)d_in[7];
  float* out = (float*)d_out;

  const int N = in_sizes[0] / DIM;
  const int E = in_sizes[1];

  const int NB = (N + RPB - 1) / RPB;   // row buckets
  const int NC = NB * NCHUNK;           // (bucket, chunk) counters
  const int nblk_scan = (NC + 2047) / 2048;
  const int cpb = (E + NCHUNK - 1) / NCHUNK;

  size_t int_words = (size_t)NC + 256 + (NB + 1) + (N + 1);
  size_t u2_off = ((int_words * sizeof(int)) + 15) & ~(size_t)15;
  size_t need_base = u2_off + 2 * (size_t)E * sizeof(uint2);
  size_t xh_off = (need_base + 15) & ~(size_t)15;
  size_t need_fp16 = xh_off + (size_t)N * DIM * sizeof(__half);

  if (ws_size >= need_base && NB <= MAXBUK && nblk_scan <= 256) {
    int* counts = (int*)d_ws;                       // NC
    int* partials = counts + NC;                    // 256
    int* bucket_base = partials + 256;              // NB+1
    int* row_start = bucket_base + (NB + 1);        // N+1
    uint2* binned = (uint2*)((char*)d_ws + u2_off); // E
    uint2* csr = binned + E;                        // E
    const bool use_fp16 = (ws_size >= need_fp16);
    __half* xh = (__half*)((char*)d_ws + xh_off);

    if (use_fp16) {
      int n4 = N * DIM / 4;
      cvt_x_kernel<<<(n4 + 255) / 256, 256, 0, stream>>>(x, xh, n4);
    }
    count_coarse<<<NCHUNK, 256, 0, stream>>>(erow, counts, E, cpb, NB);
    scan1b_kernel<<<nblk_scan, 256, 0, stream>>>(counts, partials, NC);
    scan2_kernel<<<1, 256, 0, stream>>>(partials, nblk_scan);
    scan3b_kernel<<<(NC + 255) / 256, 256, 0, stream>>>(counts, partials,
                                                        bucket_base, NC, NB, E);
    scatter_coarse<<<NCHUNK, 256, 0, stream>>>(erow, ecol, eval, counts,
                                               binned, E, cpb, NB);
    sort_fine<<<NB, 256, 0, stream>>>(binned, bucket_base, csr, row_start, N,
                                      E);
    const int fblocks = (N + 63) / 64;
    if (use_fp16) {
      fused_gather_mfma_ln<__half><<<fblocks, 256, 0, stream>>>(
          xh, csr, row_start, W, bias, gamma, beta, out, N);
    } else {
      fused_gather_mfma_ln<float><<<fblocks, 256, 0, stream>>>(
          x, csr, row_start, W, bias, gamma, beta, out, N);
    }
  } else {
    const size_t agg_bytes = (size_t)N * DIM * sizeof(float);
    float* agg = (ws_size >= agg_bytes) ? (float*)d_ws : out;
    hipMemsetAsync(agg, 0, agg_bytes, stream);
    long long total = (long long)E * 16;
    int blocks = (int)((total + 255) / 256);
    scatter_kernel<<<blocks, 256, 0, stream>>>(x, erow, ecol, eval, agg, E);
    fused_linear_ln_relu<<<(N + 15) / 16, 256, 0, stream>>>(agg, W, bias,
                                                            gamma, beta, out, N);
  }
}

// Round 8
// 113.544 us; speedup vs baseline: 1.2754x; 1.1425x over previous
//
#include <hip/hip_runtime.h>
#include <hip/hip_fp16.h>

#define DIM 64
#define RPB 128          // rows per bucket
#define NCHUNK 256       // edge chunks for count/scatter passes
#define MAXBUK 1024      // max buckets supported by LDS counters

typedef _Float16 half8_t __attribute__((ext_vector_type(8)));
typedef float f32x4_t __attribute__((ext_vector_type(4)));

__device__ __forceinline__ float readlane_f(float v, int l) {
  return __uint_as_float(__builtin_amdgcn_readlane(__float_as_uint(v), l));
}

// XCD-contiguous chunk mapping: XCD k (blockIdx%8) handles contiguous chunks.
__device__ __forceinline__ int chunk_id(int blk) {
  return (blk & 7) * (NCHUNK / 8) + (blk >> 3);
}

// ===========================================================================
// Fallback path (tiny workspace): atomic scatter + fused linear/LN/ReLU
// ===========================================================================
__global__ __launch_bounds__(256) void scatter_kernel(
    const float* __restrict__ x, const int* __restrict__ erow,
    const int* __restrict__ ecol, const float* __restrict__ eval,
    float* __restrict__ agg, int E) {
  int t = blockIdx.x * 256 + threadIdx.x;
  int e = t >> 4;
  if (e >= E) return;
  int lid = t & 15;
  int r = erow[e];
  int c = ecol[e];
  float v = eval[e];
  const float4 xv =
      *reinterpret_cast<const float4*>(x + (size_t)c * DIM + lid * 4);
  float* dst = agg + (size_t)r * DIM + lid * 4;
  atomicAdd(dst + 0, v * xv.x);
  atomicAdd(dst + 1, v * xv.y);
  atomicAdd(dst + 2, v * xv.z);
  atomicAdd(dst + 3, v * xv.w);
}

__global__ __launch_bounds__(256) void fused_linear_ln_relu(
    const float* __restrict__ agg, const float* __restrict__ W,
    const float* __restrict__ bias, const float* __restrict__ gamma,
    const float* __restrict__ beta, float* __restrict__ out, int N) {
  __shared__ float Wt[64 * 65];
  for (int i = threadIdx.x; i < 64 * 64; i += 256) {
    int d = i >> 6, k = i & 63;
    Wt[k * 65 + d] = W[i];
  }
  __syncthreads();

  const int wave = threadIdx.x >> 6;
  const int lane = threadIdx.x & 63;
  const int node0 = blockIdx.x * 16 + wave * 4;

  float a0 = 0.f, a1 = 0.f, a2 = 0.f, a3 = 0.f;
  if (node0 + 0 < N) a0 = agg[(size_t)(node0 + 0) * DIM + lane];
  if (node0 + 1 < N) a1 = agg[(size_t)(node0 + 1) * DIM + lane];
  if (node0 + 2 < N) a2 = agg[(size_t)(node0 + 2) * DIM + lane];
  if (node0 + 3 < N) a3 = agg[(size_t)(node0 + 3) * DIM + lane];

  float acc0 = 0.f, acc1 = 0.f, acc2 = 0.f, acc3 = 0.f;
#pragma unroll
  for (int k = 0; k < 64; ++k) {
    float w = Wt[k * 65 + lane];
    acc0 = fmaf(readlane_f(a0, k), w, acc0);
    acc1 = fmaf(readlane_f(a1, k), w, acc1);
    acc2 = fmaf(readlane_f(a2, k), w, acc2);
    acc3 = fmaf(readlane_f(a3, k), w, acc3);
  }

  const float bv = bias[lane];
  const float gv = gamma[lane];
  const float btv = beta[lane];
  float accs[4] = {acc0, acc1, acc2, acc3};
#pragma unroll
  for (int j = 0; j < 4; ++j) {
    int node = node0 + j;
    if (node >= N) continue;
    float h = accs[j] + bv;
    float s1 = h, s2 = h * h;
#pragma unroll
    for (int off = 32; off; off >>= 1) {
      s1 += __shfl_xor(s1, off, 64);
      s2 += __shfl_xor(s2, off, 64);
    }
    float mu = s1 * (1.0f / 64.0f);
    float var = s2 * (1.0f / 64.0f) - mu * mu;
    float inv = rsqrtf(var + 1e-5f);
    float y = (h - mu) * inv * gv + btv;
    out[(size_t)node * DIM + lane] = fmaxf(y, 0.0f);
  }
}

// ===========================================================================
// 1) merged: per-chunk bucket histogram (blocks < NCHUNK)  ||  x->fp16 mirror
//    (blocks >= NCHUNK). Overlaps the BW-bound cvt under the atomic-bound
//    count instead of serializing two launches.
// ===========================================================================
__global__ __launch_bounds__(256) void count_and_cvt(
    const int* __restrict__ erow, int* __restrict__ counts, int E, int cpb,
    int NB, const float* __restrict__ x, __half* __restrict__ xh, int n4) {
  if (blockIdx.x >= NCHUNK) {
    int i = (blockIdx.x - NCHUNK) * 256 + threadIdx.x;
    if (i < n4) {
      float4 f = reinterpret_cast<const float4*>(x)[i];
      __half2 a = __floats2half2_rn(f.x, f.y);
      __half2 b = __floats2half2_rn(f.z, f.w);
      uint2 o;
      o.x = *reinterpret_cast<unsigned*>(&a);
      o.y = *reinterpret_cast<unsigned*>(&b);
      reinterpret_cast<uint2*>(xh)[i] = o;
    }
    return;
  }
  __shared__ int cnt[MAXBUK];
  for (int i = threadIdx.x; i < NB; i += 256) cnt[i] = 0;
  __syncthreads();
  const int cid = chunk_id(blockIdx.x);
  const int base = cid * cpb;
  const int end = min(E, base + cpb);
  for (int e = base + threadIdx.x; e < end; e += 256)
    atomicAdd(&cnt[erow[e] >> 7], 1);
  __syncthreads();
  for (int i = threadIdx.x; i < NB; i += 256)
    counts[i * NCHUNK + cid] = cnt[i];
}

// ===========================================================================
// Two-level deterministic-position sort (unchanged)
// ===========================================================================
__global__ __launch_bounds__(256) void scan1b_kernel(int* __restrict__ data,
                                                     int* __restrict__ partials,
                                                     int n) {
  __shared__ int wsum[4];
  const int t = threadIdx.x;
  const int base = blockIdx.x * 2048 + t * 8;
  int v[8];
  int s = 0;
#pragma unroll
  for (int j = 0; j < 8; ++j) {
    v[j] = (base + j < n) ? data[base + j] : 0;
    s += v[j];
  }
  int ps = s;
  const int lane = t & 63;
#pragma unroll
  for (int off = 1; off < 64; off <<= 1) {
    int nn = __shfl_up(ps, off, 64);
    if (lane >= off) ps += nn;
  }
  if (lane == 63) wsum[t >> 6] = ps;
  __syncthreads();
  int woff = 0;
  for (int w = 0; w < (t >> 6); ++w) woff += wsum[w];
  int ex = woff + ps - s;
#pragma unroll
  for (int j = 0; j < 8; ++j) {
    if (base + j < n) data[base + j] = ex;
    ex += v[j];
  }
  if (t == 255) partials[blockIdx.x] = woff + ps;
}

__global__ __launch_bounds__(256) void scan2_kernel(int* __restrict__ partials,
                                                    int nb) {
  __shared__ int wsum[4];
  int t = threadIdx.x;
  int v = (t < nb) ? partials[t] : 0;
  int ps = v;
  int lane = t & 63;
#pragma unroll
  for (int off = 1; off < 64; off <<= 1) {
    int n = __shfl_up(ps, off, 64);
    if (lane >= off) ps += n;
  }
  if (lane == 63) wsum[t >> 6] = ps;
  __syncthreads();
  int woff = 0;
  for (int w = 0; w < (t >> 6); ++w) woff += wsum[w];
  if (t < nb) partials[t] = woff + ps - v;
}

__global__ __launch_bounds__(256) void scan3b_kernel(
    int* __restrict__ data, const int* __restrict__ partials,
    int* __restrict__ bucket_base, int NC, int NB, int E) {
  int i = blockIdx.x * 256 + threadIdx.x;
  if (i < NC) {
    int v = data[i] + partials[i >> 11];
    data[i] = v;
    if ((i & (NCHUNK - 1)) == 0) bucket_base[i / NCHUNK] = v;
  }
  if (i == 0) bucket_base[NB] = E;
}

__global__ __launch_bounds__(256) void scatter_coarse(
    const int* __restrict__ erow, const int* __restrict__ ecol,
    const float* __restrict__ eval, const int* __restrict__ scanned,
    uint2* __restrict__ binned, int E, int cpb, int NB) {
  __shared__ int cur[MAXBUK];
  const int cid = chunk_id(blockIdx.x);
  for (int i = threadIdx.x; i < NB; i += 256)
    cur[i] = scanned[i * NCHUNK + cid];
  __syncthreads();
  const int base = cid * cpb;
  const int end = min(E, base + cpb);
  for (int e = base + threadIdx.x; e < end; e += 256) {
    int r = erow[e];
    uint2 p;
    p.x = ((unsigned)ecol[e] << 7) | (unsigned)(r & 127);
    p.y = __float_as_uint(eval[e]);
    int pos = atomicAdd(&cur[r >> 7], 1);
    binned[pos] = p;
  }
}

__global__ __launch_bounds__(256) void sort_fine(
    const uint2* __restrict__ binned, const int* __restrict__ bucket_base,
    uint2* __restrict__ csr, int* __restrict__ row_start, int N, int E) {
  __shared__ int hist[RPB];
  __shared__ int cursor[RPB];
  const int b = blockIdx.x;
  const int s = bucket_base[b];
  const int en = bucket_base[b + 1];
  const int t = threadIdx.x;
  if (t < RPB) hist[t] = 0;
  __syncthreads();
  for (int e = s + t; e < en; e += 256)
    atomicAdd(&hist[binned[e].x & 127], 1);
  __syncthreads();
  if (t == 0) {
    int run = 0;
    for (int i = 0; i < RPB; ++i) {
      int c = hist[i];
      cursor[i] = run;
      run += c;
    }
  }
  __syncthreads();
  if (t < RPB) {
    int node = b * RPB + t;
    if (node < N) row_start[node] = s + cursor[t];
  }
  if (b == 0 && t == 0) row_start[N] = E;
  __syncthreads();
  for (int e = s + t; e < en; e += 256) {
    uint2 p = binned[e];
    int rl = (int)(p.x & 127);
    int pos = s + atomicAdd(&cursor[rl], 1);
    uint2 q;
    q.x = p.x >> 7;  // col
    q.y = p.y;       // val bits
    csr[pos] = q;
  }
}

// ===========================================================================
// Fused gather (clamped ILP-8) + MFMA Linear + LayerNorm + ReLU.
// One block = 4 waves; each wave owns 16 nodes (decoupled after the early
// barrier: gather writes only the wave's own A_lds slice, MFMA reads it).
// ===========================================================================
template <typename XT>
__global__ __launch_bounds__(256) void fused_gather_mfma_ln(
    const XT* __restrict__ xg, const uint2* __restrict__ csr,
    const int* __restrict__ row_start, const float* __restrict__ W,
    const float* __restrict__ bias, const float* __restrict__ gamma,
    const float* __restrict__ beta, float* __restrict__ out, int N) {
  __shared__ _Float16 Wp[4 * 2 * 64 * 8];   // B fragments, 8 KB
  __shared__ _Float16 A_lds[4][16 * 72];    // per-wave A tile, 9 KB total

  const int tid = threadIdx.x;

  // Pack W into B-fragment order: Wp[((t*2+h)*64+l)*8 + j] =
  //   W[d][k],  d=(l&15)+16t, k=8*(l>>4)+j+32h
  for (int p = tid; p < 512; p += 256) {
    int t = p >> 7, h = (p >> 6) & 1, l = p & 63;
    int d = (l & 15) + 16 * t;
    int k0 = ((l >> 4) << 3) + 32 * h;
    const float* wr = W + d * 64 + k0;
    _Float16* dst = &Wp[p * 8];
#pragma unroll
    for (int j = 0; j < 8; ++j) dst[j] = (_Float16)wr[j];
  }
  __syncthreads();  // only cross-wave dependency: Wp

  const int wave = tid >> 6;
  const int lane = tid & 63;
  const int g = lane >> 4;   // gather group
  const int lid = lane & 15; // 16 lanes x 4 dims = 64 k's
  const int wbase = blockIdx.x * 64 + wave * 16;

  // ---- gather: each group does 4 nodes sequentially; clamped ILP-8 ----
#pragma unroll 1
  for (int m = 0; m < 4; ++m) {
    const int row = g * 4 + m;
    const int node = wbase + row;
    float4 acc = make_float4(0.f, 0.f, 0.f, 0.f);
    if (node < N) {
      const int s = row_start[node];
      const int en = row_start[node + 1];
#pragma unroll 1
      for (int j = s; j < en; j += 8) {
        uint2 p[8];
#pragma unroll
        for (int i = 0; i < 8; ++i) {
          int idx = j + i;
          idx = idx < en ? idx : en - 1;
          p[i] = csr[idx];
        }
        if constexpr (sizeof(XT) == 2) {
          uint2 xv[8];
#pragma unroll
          for (int i = 0; i < 8; ++i)
            xv[i] = *reinterpret_cast<const uint2*>(xg + (size_t)p[i].x * DIM +
                                                    lid * 4);
#pragma unroll
          for (int i = 0; i < 8; ++i) {
            float v = (j + i < en) ? __uint_as_float(p[i].y) : 0.0f;
            float2 f01 = __half22float2(*reinterpret_cast<__half2*>(&xv[i].x));
            float2 f23 = __half22float2(*reinterpret_cast<__half2*>(&xv[i].y));
            acc.x = fmaf(v, f01.x, acc.x);
            acc.y = fmaf(v, f01.y, acc.y);
            acc.z = fmaf(v, f23.x, acc.z);
            acc.w = fmaf(v, f23.y, acc.w);
          }
        } else {
          float4 xv[8];
#pragma unroll
          for (int i = 0; i < 8; ++i)
            xv[i] = *reinterpret_cast<const float4*>(
                (const float*)xg + (size_t)p[i].x * DIM + lid * 4);
#pragma unroll
          for (int i = 0; i < 8; ++i) {
            float v = (j + i < en) ? __uint_as_float(p[i].y) : 0.0f;
            acc.x = fmaf(v, xv[i].x, acc.x);
            acc.y = fmaf(v, xv[i].y, acc.y);
            acc.z = fmaf(v, xv[i].z, acc.z);
            acc.w = fmaf(v, xv[i].w, acc.w);
          }
        }
      }
    }
    __half2 lo = __floats2half2_rn(acc.x, acc.y);
    __half2 hi = __floats2half2_rn(acc.z, acc.w);
    uint2 pk;
    pk.x = *reinterpret_cast<unsigned*>(&lo);
    pk.y = *reinterpret_cast<unsigned*>(&hi);
    *reinterpret_cast<uint2*>(&A_lds[wave][row * 72 + lid * 4]) = pk;
  }

  // Wave-local RAW on A_lds: drain DS queue, then pin the order (rule 18).
  asm volatile("s_waitcnt lgkmcnt(0)" ::: "memory");
  __builtin_amdgcn_sched_barrier(0);

  // ---- MFMA: 16 nodes x 64 dims = 4 dim-tiles x 2 K-halves ----
  half8_t bf[4][2];
#pragma unroll
  for (int t = 0; t < 4; ++t)
#pragma unroll
    for (int h = 0; h < 2; ++h)
      bf[t][h] =
          *reinterpret_cast<const half8_t*>(&Wp[((t * 2 + h) * 64 + lane) * 8]);

  const int arow = lane & 15;
  const int koff = (lane >> 4) * 8;
  half8_t a0 =
      *reinterpret_cast<const half8_t*>(&A_lds[wave][arow * 72 + koff]);
  half8_t a1 =
      *reinterpret_cast<const half8_t*>(&A_lds[wave][arow * 72 + koff + 32]);

  f32x4_t dacc[4];
#pragma unroll
  for (int t = 0; t < 4; ++t) {
    f32x4_t z = {0.f, 0.f, 0.f, 0.f};
    z = __builtin_amdgcn_mfma_f32_16x16x32_f16(a0, bf[t][0], z, 0, 0, 0);
    z = __builtin_amdgcn_mfma_f32_16x16x32_f16(a1, bf[t][1], z, 0, 0, 0);
    dacc[t] = z;
  }

  // ---- epilogue: bias + LN + ReLU ----
  const int q = lane >> 4;   // node quadrant
  const int c = lane & 15;   // dim low
  float bv[4], gv[4], btv[4];
#pragma unroll
  for (int t = 0; t < 4; ++t) {
    int d = c + 16 * t;
    bv[t] = bias[d];
    gv[t] = gamma[d];
    btv[t] = beta[d];
  }

#pragma unroll
  for (int j = 0; j < 4; ++j) {
    const int node = wbase + q * 4 + j;
    float h0 = dacc[0][j] + bv[0];
    float h1 = dacc[1][j] + bv[1];
    float h2 = dacc[2][j] + bv[2];
    float h3 = dacc[3][j] + bv[3];
    float s1 = h0 + h1 + h2 + h3;
    float s2 = fmaf(h0, h0, fmaf(h1, h1, fmaf(h2, h2, h3 * h3)));
#pragma unroll
    for (int off = 1; off < 16; off <<= 1) {
      s1 += __shfl_xor(s1, off, 16);
      s2 += __shfl_xor(s2, off, 16);
    }
    float mu = s1 * (1.0f / 64.0f);
    float var = s2 * (1.0f / 64.0f) - mu * mu;
    float inv = rsqrtf(var + 1e-5f);
    if (node < N) {
      float* o = out + (size_t)node * DIM + c;
      o[0]  = fmaxf((h0 - mu) * inv * gv[0] + btv[0], 0.f);
      o[16] = fmaxf((h1 - mu) * inv * gv[1] + btv[1], 0.f);
      o[32] = fmaxf((h2 - mu) * inv * gv[2] + btv[2], 0.f);
      o[48] = fmaxf((h3 - mu) * inv * gv[3] + btv[3], 0.f);
    }
  }
}

// ===========================================================================
extern "C" void kernel_launch(void* const* d_in, const int* in_sizes, int n_in,
                              void* d_out, int out_size, void* d_ws,
                              size_t ws_size, hipStream_t stream) {
  const float* x = (const float*)d_in[0];
  const int* erow = (const int*)d_in[1];
  const int* ecol = (const int*)d_in[2];
  const float* eval = (const float*)d_in[3];
  const float* W = (const float*)d_in[4];
  const float* bias = (const float*)d_in[5];
  const float* gamma = (const float*)d_in[6];
  const float* beta = (const float*)d_in[7];
  float* out = (float*)d_out;

  const int N = in_sizes[0] / DIM;
  const int E = in_sizes[1];

  const int NB = (N + RPB - 1) / RPB;   // row buckets
  const int NC = NB * NCHUNK;           // (bucket, chunk) counters
  const int nblk_scan = (NC + 2047) / 2048;
  const int cpb = (E + NCHUNK - 1) / NCHUNK;

  size_t int_words = (size_t)NC + 256 + (NB + 1) + (N + 1);
  size_t u2_off = ((int_words * sizeof(int)) + 15) & ~(size_t)15;
  size_t need_base = u2_off + 2 * (size_t)E * sizeof(uint2);
  size_t xh_off = (need_base + 15) & ~(size_t)15;
  size_t need_fp16 = xh_off + (size_t)N * DIM * sizeof(__half);

  if (ws_size >= need_base && NB <= MAXBUK && nblk_scan <= 256) {
    int* counts = (int*)d_ws;                       // NC
    int* partials = counts + NC;                    // 256
    int* bucket_base = partials + 256;              // NB+1
    int* row_start = bucket_base + (NB + 1);        // N+1
    uint2* binned = (uint2*)((char*)d_ws + u2_off); // E
    uint2* csr = binned + E;                        // E
    const bool use_fp16 = (ws_size >= need_fp16);
    __half* xh = (__half*)((char*)d_ws + xh_off);

    const int n4 = use_fp16 ? (N * DIM / 4) : 0;
    const int cvt_blocks = use_fp16 ? (n4 + 255) / 256 : 0;
    count_and_cvt<<<NCHUNK + cvt_blocks, 256, 0, stream>>>(
        erow, counts, E, cpb, NB, x, xh, n4);
    scan1b_kernel<<<nblk_scan, 256, 0, stream>>>(counts, partials, NC);
    scan2_kernel<<<1, 256, 0, stream>>>(partials, nblk_scan);
    scan3b_kernel<<<(NC + 255) / 256, 256, 0, stream>>>(counts, partials,
                                                        bucket_base, NC, NB, E);
    scatter_coarse<<<NCHUNK, 256, 0, stream>>>(erow, ecol, eval, counts,
                                               binned, E, cpb, NB);
    sort_fine<<<NB, 256, 0, stream>>>(binned, bucket_base, csr, row_start, N,
                                      E);
    const int fblocks = (N + 63) / 64;
    if (use_fp16) {
      fused_gather_mfma_ln<__half><<<fblocks, 256, 0, stream>>>(
          xh, csr, row_start, W, bias, gamma, beta, out, N);
    } else {
      fused_gather_mfma_ln<float><<<fblocks, 256, 0, stream>>>(
          x, csr, row_start, W, bias, gamma, beta, out, N);
    }
  } else {
    const size_t agg_bytes = (size_t)N * DIM * sizeof(float);
    float* agg = (ws_size >= agg_bytes) ? (float*)d_ws : out;
    hipMemsetAsync(agg, 0, agg_bytes, stream);
    long long total = (long long)E * 16;
    int blocks = (int)((total + 255) / 256);
    scatter_kernel<<<blocks, 256, 0, stream>>>(x, erow, ecol, eval, agg, E);
    fused_linear_ln_relu<<<(N + 15) / 16, 256, 0, stream>>>(agg, W, bias,
                                                            gamma, beta, out, N);
  }
}